// Round 13
// baseline (266.276 us; speedup 1.0000x reference)
//
#include <hip/hip_runtime.h>
#include <hip/hip_bf16.h>
#include <math.h>

// Channel attention: x (2,16,16,16,64) fp32 -> B=2, N=4096, C=64.
// out = gamma * softmax(QQ^T) Q + x.
// v13: v9 attn (best known, 81.9us) + epilogue fused into attn via per-row-
// group arrival counters (last of S blocks runs the 64-row epi inline).
// Tier A = 2 dispatches (prep zeroes counters; attn does merge+output).
// Evidence: R11 counters show MFMA busy 3.3us; the ~25us attn wall across 7
// structural variants is latency at a post-fill DVFS-depressed clock; the
// only remaining controllable term is dispatch count/gaps.
// Fixed harness floor: ~42us d_ws re-poison fill inside the timed window.

#define NN 4096
#define CC 64
#define LOG2E 1.4426950408889634f

typedef __attribute__((ext_vector_type(4))) float f32x4;
typedef __attribute__((ext_vector_type(8))) short bf16x8;
typedef __attribute__((ext_vector_type(4))) short bf16x4;
typedef unsigned short u16;
typedef __attribute__((ext_vector_type(4))) u16 u16x4;
typedef __attribute__((ext_vector_type(2))) unsigned u32x2;

__device__ inline u16 f2bf(float f) {  // RNE
  union { float f; unsigned u; } v; v.f = f;
  unsigned r = (v.u + 0x7fffu + ((v.u >> 16) & 1u)) >> 16;
  return (u16)r;
}
__device__ inline float bf2f(short h) {
  union { unsigned u; float f; } v;
  v.u = ((unsigned)(unsigned short)h) << 16;
  return v.f;
}
__device__ inline unsigned fbits(float f) {
  union { float f; unsigned u; } v; v.f = f;
  return v.u;
}
__device__ inline bf16x8 cvt8(f32x4 a, f32x4 b) {
  bf16x8 r;
  r[0] = (short)f2bf(a[0]); r[1] = (short)f2bf(a[1]);
  r[2] = (short)f2bf(a[2]); r[3] = (short)f2bf(a[3]);
  r[4] = (short)f2bf(b[0]); r[5] = (short)f2bf(b[1]);
  r[6] = (short)f2bf(b[2]); r[7] = (short)f2bf(b[3]);
  return r;
}

// ---------------------------------------------------------------------------
// Prep: x -> bf16 Qb[b][n][c] and Vt2[b][n/64][c][n%64]. 128 blocks x 256.
// Block 0 also zeroes the 128 arrival counters (prep completes before attn).
// ---------------------------------------------------------------------------
__global__ __launch_bounds__(256) void prep_kernel(const float* __restrict__ x,
                                                   u16* __restrict__ Qb,
                                                   u16* __restrict__ Vt,
                                                   int* __restrict__ cnt) {
  __shared__ u16 t[64][68];
  const int id = blockIdx.x;
  if (id == 0 && threadIdx.x < 128) cnt[threadIdx.x] = 0;
  const int b = id >> 6;
  const int kb64 = id & 63;
  const int n0 = kb64 * 64;
  const f32x4* x4 = (const f32x4*)(x + ((size_t)b * NN + n0) * CC);
  u16* qb = Qb + ((size_t)b * NN + n0) * CC;
#pragma unroll
  for (int it = 0; it < 4; ++it) {
    int idx4 = it * 256 + threadIdx.x;  // [0,1024) = 64 rows x 16 groups
    int i = idx4 >> 4, cgi = idx4 & 15;
    f32x4 v = x4[idx4];
    u16x4 h;
    h[0] = f2bf(v[0]); h[1] = f2bf(v[1]); h[2] = f2bf(v[2]); h[3] = f2bf(v[3]);
    *(u16x4*)(qb + (size_t)idx4 * 4) = h;
    t[cgi * 4 + 0][i] = h[0]; t[cgi * 4 + 1][i] = h[1];
    t[cgi * 4 + 2][i] = h[2]; t[cgi * 4 + 3][i] = h[3];
  }
  __syncthreads();
  u16* vt = Vt + ((size_t)b * (NN / 64) + kb64) * (64 * 64);
#pragma unroll
  for (int it = 0; it < 4; ++it) {
    int idx4 = it * 256 + threadIdx.x;
    int c = idx4 >> 4, i4 = (idx4 & 15) * 4;
    u16x4 h = *(const u16x4*)(&t[c][i4]);
    *(u16x4*)(vt + c * 64 + i4) = h;
  }
}

// ---------------------------------------------------------------------------
// attn+epi: v9 body (4 waves x 16 rows = 64 rows/block, S slices, gll-staged
// XOR-swizzled LDS dbuf). After partials: fence + atomicAdd; the last of the
// S blocks for a (b,rg) row-group runs the epilogue for its 64 rows inline.
// ---------------------------------------------------------------------------
template <int S>
__global__ __launch_bounds__(256, 4) void attn_split(
    const float* __restrict__ x, const float* __restrict__ gamma,
    const u16* __restrict__ Qb, const u16* __restrict__ Vt,
    u16* __restrict__ Opart, float* __restrict__ lpart,
    int* __restrict__ cnt, float* __restrict__ out) {
  constexpr int KPS = NN / S;        // 512
  constexpr int ITERS = KPS / 64;    // 8
  const int w = threadIdx.x >> 6;    // 0..3
  const int lane = threadIdx.x & 63;
  const int quad = lane >> 4, col = lane & 15;
  const int blk = blockIdx.x;        // [0, 2*64*S)
  const int b = blk / (64 * S);
  const int rg = (blk / S) & 63;
  const int s = blk % S;

  __shared__ u16 KT[2][64 * 64];     // 16 KB, XOR-swizzled chunks
  __shared__ u16 VT[2][64 * 64];     // 16 KB
  __shared__ u16 PB[4][16 * 64];     // 8 KB (reused as epi flag after loop)

  const u16* Qbase = Qb + (size_t)b * NN * CC;
  const u16* Vbase = Vt + (size_t)b * NN * CC;  // [NN/64][64][64]
  const int row0 = rg * 64 + w * 16;

  // --- Q B-frag (pre-scaled by log2e); m = diag of scaled S (scalar/lane) ---
  bf16x8 qs0, qs1;
  float m_sc;
  {
    const u16* qp = Qbase + (size_t)(row0 + col) * CC + quad * 8;
    bf16x8 r0 = *(const bf16x8*)qp;
    bf16x8 r1 = *(const bf16x8*)(qp + 32);
    float msum = 0.f;
#pragma unroll
    for (int j = 0; j < 8; ++j) {
      float a0 = bf2f(r0[j]), a1 = bf2f(r1[j]);
      u16 h0 = f2bf(a0 * LOG2E), h1 = f2bf(a1 * LOG2E);
      qs0[j] = (short)h0; qs1[j] = (short)h1;
      msum += bf2f((short)h0) * a0 + bf2f((short)h1) * a1;
    }
    msum += __shfl_xor(msum, 16);
    msum += __shfl_xor(msum, 32);  // every lane: full diag for qrow=col
    m_sc = msum;
  }

  f32x4 zero = {0.f, 0.f, 0.f, 0.f};
  f32x4 acc[4] = {zero, zero, zero, zero};
  float l_loc = 0.f;

  // --- staging: wave w covers keys/chs [w*16, w*16+16) of the 64-tile ---
  const int kk = lane >> 3;
  const int sw = (lane & 7) ^ kk;
  const u16* kptr = Qbase + (size_t)(s * KPS + w * 16 + kk) * CC + sw * 8;
  const u16* vptr = Vbase + ((size_t)(s * KPS >> 6) * 64 + (w * 16 + kk)) * 64 + sw * 8;

#define STAGE(p, kp, vp)                                                      \
  {                                                                           \
    _Pragma("unroll")                                                         \
    for (int g = 0; g < 2; ++g) {                                             \
      __builtin_amdgcn_global_load_lds(                                       \
          (const __attribute__((address_space(1))) unsigned*)((kp) + g * 512),\
          (__attribute__((address_space(3))) unsigned*)&KT[p][(w * 16 + g * 8) * 64], \
          16, 0, 0);                                                          \
      __builtin_amdgcn_global_load_lds(                                       \
          (const __attribute__((address_space(1))) unsigned*)((vp) + g * 512),\
          (__attribute__((address_space(3))) unsigned*)&VT[p][(w * 16 + g * 8) * 64], \
          16, 0, 0);                                                          \
    }                                                                         \
  }

  STAGE(0, kptr, vptr)
  const int cs = col & 7;
  u16* PBw = &PB[w][0];
#pragma unroll 2
  for (int i = 0; i < ITERS; ++i) {
    __syncthreads();  // own vmcnt drained pre-barrier -> tile i ready
    const int p = i & 1;
    if (i + 1 < ITERS) STAGE(p ^ 1, kptr + 4096, vptr + 4096)
    kptr += 4096; vptr += 4096;

    // --- QK^T (S^T form: A=K, B=Q) + exp2 + swizzled packed P-write ---
    f32x4 sx[4];
#pragma unroll
    for (int t = 0; t < 4; ++t) {
      bf16x8 ka = *(const bf16x8*)&KT[p][(t * 16 + col) * 64 + (quad ^ cs) * 8];
      bf16x8 kb = *(const bf16x8*)&KT[p][(t * 16 + col) * 64 + ((quad + 4) ^ cs) * 8];
      sx[t] = __builtin_amdgcn_mfma_f32_16x16x32_bf16(ka, qs0, zero, 0, 0, 0);
      sx[t] = __builtin_amdgcn_mfma_f32_16x16x32_bf16(kb, qs1, sx[t], 0, 0, 0);
    }
#pragma unroll
    for (int t = 0; t < 4; ++t) {
      f32x4 pv;
#pragma unroll
      for (int r = 0; r < 4; ++r) pv[r] = exp2f(sx[t][r] - m_sc);
      l_loc += pv[0] + pv[1] + pv[2] + pv[3];
      u32x2 d;
      d[0] = __builtin_amdgcn_perm(fbits(pv[1]), fbits(pv[0]), 0x07060302u);
      d[1] = __builtin_amdgcn_perm(fbits(pv[3]), fbits(pv[2]), 0x07060302u);
      *(u32x2*)&PBw[col * 64 + ((t * 2 + (quad >> 1)) ^ cs) * 8 + (quad & 1) * 4] = d;
    }
    bf16x8 pf0 = *(const bf16x8*)&PBw[col * 64 + (quad ^ cs) * 8];
    bf16x8 pf1 = *(const bf16x8*)&PBw[col * 64 + ((quad + 4) ^ cs) * 8];
#pragma unroll
    for (int cgi = 0; cgi < 4; ++cgi) {
      bf16x8 va = *(const bf16x8*)&VT[p][(cgi * 16 + col) * 64 + (quad ^ cs) * 8];
      bf16x8 vb = *(const bf16x8*)&VT[p][(cgi * 16 + col) * 64 + ((quad + 4) ^ cs) * 8];
      acc[cgi] = __builtin_amdgcn_mfma_f32_16x16x32_bf16(pf0, va, acc[cgi], 0, 0, 0);
      acc[cgi] = __builtin_amdgcn_mfma_f32_16x16x32_bf16(pf1, vb, acc[cgi], 0, 0, 0);
    }
  }
#undef STAGE

  // --- finalize l (2 shuffles) and write partials ---
  size_t pbase = (((size_t)(b * 64 + rg)) * S + s) * (64 * 64);
  size_t lbase = (((size_t)(b * 64 + rg)) * S + s) * 64;
  {
    float l = l_loc;
    l += __shfl_xor(l, 16);
    l += __shfl_xor(l, 32);
    if (quad == 0) lpart[lbase + w * 16 + col] = l;
  }
#pragma unroll
  for (int r = 0; r < 4; ++r) {
    int lr = w * 16 + quad * 4 + r;
    size_t o = pbase + (size_t)lr * 64;
    Opart[o + col]      = f2bf(acc[0][r]);
    Opart[o + col + 16] = f2bf(acc[1][r]);
    Opart[o + col + 32] = f2bf(acc[2][r]);
    Opart[o + col + 48] = f2bf(acc[3][r]);
  }

  // --- arrival: last of the S blocks for (b,rg) runs the epilogue ---------
  __threadfence();  // release: partials visible device-wide before the atomic
  volatile int* flag = (volatile int*)&PB[0][0];  // PB no longer needed
  if (threadIdx.x == 0) {
    int old = atomicAdd(&cnt[b * 64 + rg], 1);  // device-scope (m20)
    *flag = (old == S - 1);
  }
  __syncthreads();
  if (*flag) {
    __threadfence();  // acquire: all S blocks' partials now visible
    float g = gamma[0];
    size_t gb = ((size_t)(b * 64 + rg)) * S;
    // 64 rows x 16 f32x4 chunks = 1024 chunks; 256 threads x 4 chunks
#pragma unroll
    for (int c = 0; c < 4; ++c) {
      int chunk = c * 256 + threadIdx.x;
      int lr = chunk >> 4, cgi = chunk & 15;
      size_t obase = gb * 4096 + (size_t)lr * 64 + cgi * 4;
      size_t lb2 = gb * 64 + lr;
      f32x4 sO = {0.f, 0.f, 0.f, 0.f};
      float sL = 0.f;
#pragma unroll
      for (int s2 = 0; s2 < S; ++s2) {
        u16x4 o4 = *(const u16x4*)(Opart + obase + (size_t)s2 * 4096);
        sL += lpart[lb2 + s2 * 64];
        sO[0] += bf2f((short)o4[0]); sO[1] += bf2f((short)o4[1]);
        sO[2] += bf2f((short)o4[2]); sO[3] += bf2f((short)o4[3]);
      }
      int n = rg * 64 + lr;
      size_t xi = (((size_t)b * NN + n) * CC + cgi * 4);
      f32x4 xv = *(const f32x4*)(x + xi);
      float inv = 1.f / sL;
      f32x4 ov;
#pragma unroll
      for (int j = 0; j < 4; ++j) ov[j] = g * (sO[j] * inv) + xv[j];
      *(f32x4*)(out + xi) = ov;
    }
  }
}

// ---------------------------------------------------------------------------
// Tier B (2MB <= ws): single-kernel path. Tier C: workspace-free.
// ---------------------------------------------------------------------------
template <int WPB>
__global__ __launch_bounds__(WPB * 64, 4) void attn_fast(
    const float* __restrict__ x, const float* __restrict__ gamma,
    const u16* __restrict__ Qb, const u16* __restrict__ Vt,
    float* __restrict__ out) {
  const int w = threadIdx.x >> 6;
  const int lane = threadIdx.x & 63;
  const int quad = lane >> 4, col = lane & 15;
  const int b = blockIdx.x >> 8;
  const int tile = (blockIdx.x & 255) << 4;

  extern __shared__ char smem[];
  float* Osh = (float*)smem;
  float* lsh = Osh + WPB * 1024;
  u16* pl = (u16*)(lsh + WPB * 16) + w * 2176;

  const size_t xoff = (size_t)b * NN * CC;
  const u16* Qbase = Qb + xoff;
  const u16* Vbase = Vt + xoff;

  bf16x8 qf0 = *(const bf16x8*)(Qbase + (size_t)(tile + col) * CC + quad * 8);
  bf16x8 qf1 = *(const bf16x8*)(Qbase + (size_t)(tile + col) * CC + 32 + quad * 8);

  float msum = 0.f;
#pragma unroll
  for (int j = 0; j < 8; ++j) {
    float a = bf2f(qf0[j]), c = bf2f(qf1[j]);
    msum += a * a + c * c;
  }
  msum += __shfl_xor(msum, 16);
  msum += __shfl_xor(msum, 32);
  float m_i[4];
#pragma unroll
  for (int r = 0; r < 4; ++r) m_i[r] = __shfl(msum, quad * 4 + r);

  f32x4 zero = {0.f, 0.f, 0.f, 0.f};
  f32x4 acc[4] = {zero, zero, zero, zero};
  float l_i[4] = {0.f, 0.f, 0.f, 0.f};

  const int k0 = w * (NN / WPB);
#pragma unroll 2
  for (int kt = k0; kt < k0 + NN / WPB; kt += 64) {
    u16* plc = pl + ((kt >> 6) & 1) * 1088;
    f32x4 sx[4];
#pragma unroll
    for (int t = 0; t < 4; ++t) {
      const u16* kp = Qbase + (size_t)(kt + t * 16 + col) * CC + quad * 8;
      bf16x8 ka = *(const bf16x8*)kp;
      bf16x8 kb = *(const bf16x8*)(kp + 32);
      sx[t] = __builtin_amdgcn_mfma_f32_16x16x32_bf16(qf0, ka, zero, 0, 0, 0);
      sx[t] = __builtin_amdgcn_mfma_f32_16x16x32_bf16(qf1, kb, sx[t], 0, 0, 0);
    }
#pragma unroll
    for (int t = 0; t < 4; ++t) {
#pragma unroll
      for (int r = 0; r < 4; ++r) {
        float p = __expf(sx[t][r] - m_i[r]);
        l_i[r] += p;
        plc[(quad * 4 + r) * 68 + t * 16 + col] = f2bf(p);
      }
    }
    bf16x8 pf0 = *(const bf16x8*)(plc + col * 68 + quad * 8);
    bf16x8 pf1 = *(const bf16x8*)(plc + col * 68 + 32 + quad * 8);
#pragma unroll
    for (int cgi = 0; cgi < 4; ++cgi) {
      const u16* vp = Vbase + (((size_t)(kt >> 6)) * 64 + cgi * 16 + col) * 64 + quad * 8;
      bf16x8 v0 = *(const bf16x8*)vp;
      bf16x8 v1 = *(const bf16x8*)(vp + 32);
      acc[cgi] = __builtin_amdgcn_mfma_f32_16x16x32_bf16(pf0, v0, acc[cgi], 0, 0, 0);
      acc[cgi] = __builtin_amdgcn_mfma_f32_16x16x32_bf16(pf1, v1, acc[cgi], 0, 0, 0);
    }
  }

#pragma unroll
  for (int r = 0; r < 4; ++r)
#pragma unroll
    for (int off = 1; off < 16; off <<= 1) l_i[r] += __shfl_xor(l_i[r], off, 16);
#pragma unroll
  for (int r = 0; r < 4; ++r) {
    int row = quad * 4 + r;
    Osh[(w * 16 + row) * 64 + col]      = acc[0][r];
    Osh[(w * 16 + row) * 64 + col + 16] = acc[1][r];
    Osh[(w * 16 + row) * 64 + col + 32] = acc[2][r];
    Osh[(w * 16 + row) * 64 + col + 48] = acc[3][r];
    if (col == 0) lsh[w * 16 + row] = l_i[r];
  }
  __syncthreads();

  float g = gamma[0];
  for (int row = w; row < 16; row += WPB) {
    float L = 0.f, val = 0.f;
#pragma unroll
    for (int w2 = 0; w2 < WPB; ++w2) {
      L += lsh[w2 * 16 + row];
      val += Osh[(w2 * 16 + row) * 64 + lane];
    }
    size_t o = xoff + (size_t)(tile + row) * CC + lane;
    out[o] = g * (val / L) + x[o];
  }
}

template <int WPB>
__global__ __launch_bounds__(512) void attn_fb(const float* __restrict__ x,
                                               const float* __restrict__ gamma,
                                               float* __restrict__ out) {
  const int w = threadIdx.x >> 6;
  const int lane = threadIdx.x & 63;
  const int quad = lane >> 4, col = lane & 15;
  const int b = blockIdx.x >> 8;
  const int tile = (blockIdx.x & 255) << 4;

  extern __shared__ char smem[];
  float* Osh = (float*)smem;
  float* msh = Osh + WPB * 1024;
  float* lsh = msh + WPB * 16;
  u16* pl = (u16*)(lsh + WPB * 16) + w * 768;
  u16* vt = (u16*)(lsh + WPB * 16) + WPB * 768 + w * 2176;

  const size_t xoff = (size_t)b * NN * CC;
  const f32x4* x4 = (const f32x4*)(x + xoff);

  bf16x8 qf0, qf1;
  {
    int ri = (tile + col) * 16 + quad * 2;
    qf0 = cvt8(x4[ri], x4[ri + 1]);
    qf1 = cvt8(x4[ri + 8], x4[ri + 9]);
  }
  f32x4 zero = {0.f, 0.f, 0.f, 0.f};
  f32x4 acc0 = zero, acc1 = zero, acc2 = zero, acc3 = zero;
  float m_i[4], l_i[4];
#pragma unroll
  for (int r = 0; r < 4; ++r) { m_i[r] = -1e30f; l_i[r] = 0.f; }

  const int k0 = w * (NN / WPB);
  for (int kt = k0; kt < k0 + NN / WPB; kt += 32) {
    bf16x8 k00, k01, k10, k11;
    {
      int kb = (kt + col) * 16 + quad * 2;
      k00 = cvt8(x4[kb], x4[kb + 1]);
      k01 = cvt8(x4[kb + 8], x4[kb + 9]);
      k10 = cvt8(x4[kb + 256], x4[kb + 257]);
      k11 = cvt8(x4[kb + 264], x4[kb + 265]);
#pragma unroll
      for (int h = 0; h < 2; ++h) {
        bf16x8 va = h ? k10 : k00, vb = h ? k11 : k01;
        int base = (h * 16 + col) * 68 + quad * 8;
        *(bf16x4*)(vt + base) = __builtin_shufflevector(va, va, 0, 1, 2, 3);
        *(bf16x4*)(vt + base + 4) = __builtin_shufflevector(va, va, 4, 5, 6, 7);
        *(bf16x4*)(vt + base + 32) = __builtin_shufflevector(vb, vb, 0, 1, 2, 3);
        *(bf16x4*)(vt + base + 36) = __builtin_shufflevector(vb, vb, 4, 5, 6, 7);
      }
    }
    f32x4 s0 = zero, s1 = zero;
    s0 = __builtin_amdgcn_mfma_f32_16x16x32_bf16(qf0, k00, s0, 0, 0, 0);
    s0 = __builtin_amdgcn_mfma_f32_16x16x32_bf16(qf1, k01, s0, 0, 0, 0);
    s1 = __builtin_amdgcn_mfma_f32_16x16x32_bf16(qf0, k10, s1, 0, 0, 0);
    s1 = __builtin_amdgcn_mfma_f32_16x16x32_bf16(qf1, k11, s1, 0, 0, 0);

    float p0[4], p1[4], alpha[4];
#pragma unroll
    for (int r = 0; r < 4; ++r) {
      float mx = fmaxf(s0[r], s1[r]);
#pragma unroll
      for (int off = 1; off < 16; off <<= 1) mx = fmaxf(mx, __shfl_xor(mx, off, 16));
      float mn = fmaxf(m_i[r], mx);
      alpha[r] = __expf(m_i[r] - mn);
      p0[r] = __expf(s0[r] - mn);
      p1[r] = __expf(s1[r] - mn);
      float rs = p0[r] + p1[r];
#pragma unroll
      for (int off = 1; off < 16; off <<= 1) rs += __shfl_xor(rs, off, 16);
      l_i[r] = l_i[r] * alpha[r] + rs;
      m_i[r] = mn;
    }
#pragma unroll
    for (int r = 0; r < 4; ++r) {
      acc0[r] *= alpha[r]; acc1[r] *= alpha[r];
      acc2[r] *= alpha[r]; acc3[r] *= alpha[r];
    }
#pragma unroll
    for (int r = 0; r < 4; ++r) {
      pl[(quad * 4 + r) * 24 + col] = f2bf(p0[r]);
      pl[384 + (quad * 4 + r) * 24 + col] = f2bf(p1[r]);
    }
    bf16x8 pf = *(const bf16x8*)(pl + (quad >> 1) * 384 + col * 24 + (quad & 1) * 8);

    bf16x8 v0, v1, v2, v3;
#pragma unroll
    for (int j = 0; j < 8; ++j) {
      int rb = (quad * 8 + j) * 68 + col;
      v0[j] = (short)vt[rb];
      v1[j] = (short)vt[rb + 16];
      v2[j] = (short)vt[rb + 32];
      v3[j] = (short)vt[rb + 48];
    }
    acc0 = __builtin_amdgcn_mfma_f32_16x16x32_bf16(pf, v0, acc0, 0, 0, 0);
    acc1 = __builtin_amdgcn_mfma_f32_16x16x32_bf16(pf, v1, acc1, 0, 0, 0);
    acc2 = __builtin_amdgcn_mfma_f32_16x16x32_bf16(pf, v2, acc2, 0, 0, 0);
    acc3 = __builtin_amdgcn_mfma_f32_16x16x32_bf16(pf, v3, acc3, 0, 0, 0);
  }

#pragma unroll
  for (int r = 0; r < 4; ++r) {
    int row = quad * 4 + r;
    Osh[(w * 16 + row) * 64 + col] = acc0[r];
    Osh[(w * 16 + row) * 64 + col + 16] = acc1[r];
    Osh[(w * 16 + row) * 64 + col + 32] = acc2[r];
    Osh[(w * 16 + row) * 64 + col + 48] = acc3[r];
    if (col == 0) { msh[w * 16 + row] = m_i[r]; lsh[w * 16 + row] = l_i[r]; }
  }
  __syncthreads();

  float g = gamma[0];
  for (int row = w; row < 16; row += WPB) {
    float M = -1e30f;
#pragma unroll
    for (int w2 = 0; w2 < WPB; ++w2) M = fmaxf(M, msh[w2 * 16 + row]);
    float L = 0.f, val = 0.f;
#pragma unroll
    for (int w2 = 0; w2 < WPB; ++w2) {
      float e = __expf(msh[w2 * 16 + row] - M);
      L += lsh[w2 * 16 + row] * e;
      val += Osh[(w2 * 16 + row) * 64 + lane] * e;
    }
    size_t o = xoff + (size_t)(tile + row) * CC + lane;
    out[o] = g * (val / L) + x[o];
  }
}

extern "C" void kernel_launch(void* const* d_in, const int* in_sizes, int n_in,
                              void* d_out, int out_size, void* d_ws, size_t ws_size,
                              hipStream_t stream) {
  const float* x = (const float*)d_in[0];
  const float* gamma = (const float*)d_in[1];
  float* out = (float*)d_out;

  constexpr int S = 8;
  constexpr size_t kQV = (size_t)2 * 2 * NN * CC * sizeof(u16);         // 2 MB
  constexpr size_t kOp = (size_t)2 * 64 * S * 64 * 64 * sizeof(u16);    // 8 MB
  constexpr size_t kLp = (size_t)2 * 64 * S * 64 * sizeof(float);       // 256 KB
  constexpr size_t kCnt = 128 * sizeof(int);                            // 512 B
  if (ws_size >= kQV + kOp + kLp + kCnt) {
    u16* Qb = (u16*)d_ws;
    u16* Vt = Qb + (size_t)2 * NN * CC;
    u16* Opart = (u16*)((char*)d_ws + kQV);
    float* lpart = (float*)((char*)d_ws + kQV + kOp);
    int* cnt = (int*)((char*)d_ws + kQV + kOp + kLp);
    prep_kernel<<<128, 256, 0, stream>>>(x, Qb, Vt, cnt);
    attn_split<S><<<2 * 64 * S, 256, 0, stream>>>(x, gamma, Qb, Vt, Opart,
                                                  lpart, cnt, out);
  } else if (ws_size >= kQV) {
    u16* Qb = (u16*)d_ws;
    u16* Vt = Qb + (size_t)2 * NN * CC;
    int* cnt = nullptr;
    (void)cnt;
    // prep without counters: reuse prep_kernel with a scratch cnt inside Qb
    // region is unsafe; simplest: point cnt at Vt tail (unused until written).
    prep_kernel<<<128, 256, 0, stream>>>(x, Qb, Vt, (int*)(Qb));  // cnt wrote
    // NOTE: block 0 zeroes 512B of Qb before writing it; prep block 0 then
    // overwrites those bytes with its own Qb data -> harmless.
    constexpr int SM = 8 * 1024 * 4 + 8 * 16 * 4 + 8 * 2176 * 2;  // 68096 B
    attn_fast<8><<<512, 512, SM, stream>>>(x, gamma, Qb, Vt, out);
  } else {
    constexpr int SM4 = 4 * (1024 + 32) * 4 + 4 * 768 * 2 + 4 * 2176 * 2;
    attn_fb<4><<<512, 256, SM4, stream>>>(x, gamma, out);
  }
}

// Round 14
// 81.652 us; speedup vs baseline: 3.2611x; 3.2611x over previous
//
#include <hip/hip_runtime.h>
#include <hip/hip_bf16.h>
#include <math.h>

// Channel attention: x (2,16,16,16,64) fp32 -> B=2, N=4096, C=64.
// out = gamma * softmax(QQ^T) Q + x.
// v14 == v9 (measured best, 81.85us): 4 waves x 16 rows = 64 rows/block, S=8,
// 1024 blocks; LDS 40KB (4 blocks/CU); launch_bounds(256,4) -> 16 waves/CU.
// S^T-form QK, XOR-swizzled KT/VT/PB, gll(16B) staging, fixed-max softmax.
// Reverted R13's threadfence/atomic epi fusion (device-scope coherence ops
// cost ~100us+ on 8 non-coherent XCD L2s — measured twice, R11+R13).
// Fixed harness floor: ~42us d_ws re-poison fill inside the timed window.

#define NN 4096
#define CC 64
#define LOG2E 1.4426950408889634f

typedef __attribute__((ext_vector_type(4))) float f32x4;
typedef __attribute__((ext_vector_type(8))) short bf16x8;
typedef __attribute__((ext_vector_type(4))) short bf16x4;
typedef unsigned short u16;
typedef __attribute__((ext_vector_type(4))) u16 u16x4;
typedef __attribute__((ext_vector_type(2))) unsigned u32x2;

__device__ inline u16 f2bf(float f) {  // RNE
  union { float f; unsigned u; } v; v.f = f;
  unsigned r = (v.u + 0x7fffu + ((v.u >> 16) & 1u)) >> 16;
  return (u16)r;
}
__device__ inline float bf2f(short h) {
  union { unsigned u; float f; } v;
  v.u = ((unsigned)(unsigned short)h) << 16;
  return v.f;
}
__device__ inline unsigned fbits(float f) {
  union { float f; unsigned u; } v; v.f = f;
  return v.u;
}
__device__ inline bf16x8 cvt8(f32x4 a, f32x4 b) {
  bf16x8 r;
  r[0] = (short)f2bf(a[0]); r[1] = (short)f2bf(a[1]);
  r[2] = (short)f2bf(a[2]); r[3] = (short)f2bf(a[3]);
  r[4] = (short)f2bf(b[0]); r[5] = (short)f2bf(b[1]);
  r[6] = (short)f2bf(b[2]); r[7] = (short)f2bf(b[3]);
  return r;
}

// ---------------------------------------------------------------------------
// Prep: x -> bf16 Qb[b][n][c] and Vt2[b][n/64][c][n%64]. 512 blocks x 256.
// ---------------------------------------------------------------------------
__global__ __launch_bounds__(256) void prep_kernel(const float* __restrict__ x,
                                                   u16* __restrict__ Qb,
                                                   u16* __restrict__ Vt) {
  __shared__ u16 t[64][20];
  int b = blockIdx.x >> 8;
  int n0 = (blockIdx.x & 255) << 4;  // 16-row tile
  const f32x4* x4 = (const f32x4*)(x + ((size_t)b * NN + n0) * CC);
  u16* qb = Qb + ((size_t)b * NN + n0) * CC;
  {
    int idx4 = threadIdx.x;          // 256 f32x4 = 16 rows x 16 groups
    int i = idx4 >> 4, cg = idx4 & 15;
    f32x4 v = x4[idx4];
    u16x4 h;
    h[0] = f2bf(v[0]); h[1] = f2bf(v[1]); h[2] = f2bf(v[2]); h[3] = f2bf(v[3]);
    *(u16x4*)(qb + (size_t)i * CC + cg * 4) = h;
    t[cg * 4 + 0][i] = h[0]; t[cg * 4 + 1][i] = h[1];
    t[cg * 4 + 2][i] = h[2]; t[cg * 4 + 3][i] = h[3];
  }
  __syncthreads();
  int kb = n0 >> 6, kw0 = n0 & 63;   // 64-key block / offset within it
  {
    int idx4 = threadIdx.x;          // 256 u16x4 = 64 c x 4 i-groups
    int c = idx4 >> 2, i4 = (idx4 & 3) * 4;
    u16x4 h = *(const u16x4*)(&t[c][i4]);
    *(u16x4*)(Vt + (((size_t)b * (NN / 64) + kb) * 64 + c) * 64 + kw0 + i4) = h;
  }
}

// ---------------------------------------------------------------------------
// Split flash v9: block = 4 waves x 16 rows = 64 rows; S key-slices.
// Each wave: ONE 16-row tile. K/V gll-staged to XOR-swizzled LDS (dbuf);
// PB XOR-swizzled, unpadded (LDS exactly 40KB).
// ---------------------------------------------------------------------------
template <int S>
__global__ __launch_bounds__(256, 4) void attn_split(
    const u16* __restrict__ Qb, const u16* __restrict__ Vt,
    u16* __restrict__ Opart, float* __restrict__ lpart) {
  constexpr int KPS = NN / S;        // 512
  constexpr int ITERS = KPS / 64;    // 8
  const int w = threadIdx.x >> 6;    // 0..3
  const int lane = threadIdx.x & 63;
  const int quad = lane >> 4, col = lane & 15;
  const int blk = blockIdx.x;        // [0, 2*64*S)
  const int b = blk / (64 * S);
  const int rg = (blk / S) & 63;
  const int s = blk % S;

  __shared__ u16 KT[2][64 * 64];     // 16 KB, XOR-swizzled chunks
  __shared__ u16 VT[2][64 * 64];     // 16 KB
  __shared__ u16 PB[4][16 * 64];     // 8 KB, per-wave, XOR-swizzled

  const u16* Qbase = Qb + (size_t)b * NN * CC;
  const u16* Vbase = Vt + (size_t)b * NN * CC;  // [NN/64][64][64]
  const int row0 = rg * 64 + w * 16;

  // --- Q B-frag (pre-scaled by log2e); m = diag of scaled S (scalar/lane) ---
  bf16x8 qs0, qs1;
  float m_sc;
  {
    const u16* qp = Qbase + (size_t)(row0 + col) * CC + quad * 8;
    bf16x8 r0 = *(const bf16x8*)qp;
    bf16x8 r1 = *(const bf16x8*)(qp + 32);
    float msum = 0.f;
#pragma unroll
    for (int j = 0; j < 8; ++j) {
      float a0 = bf2f(r0[j]), a1 = bf2f(r1[j]);
      u16 h0 = f2bf(a0 * LOG2E), h1 = f2bf(a1 * LOG2E);
      qs0[j] = (short)h0; qs1[j] = (short)h1;
      msum += bf2f((short)h0) * a0 + bf2f((short)h1) * a1;
    }
    msum += __shfl_xor(msum, 16);
    msum += __shfl_xor(msum, 32);  // every lane: full diag for qrow=col
    m_sc = msum;
  }

  f32x4 zero = {0.f, 0.f, 0.f, 0.f};
  f32x4 acc[4] = {zero, zero, zero, zero};
  float l_loc = 0.f;

  // --- staging: wave w covers keys/chs [w*16, w*16+16) of the 64-tile ---
  const int kk = lane >> 3;          // 0..7 local row in 8-row group
  const int sw = (lane & 7) ^ kk;    // XOR-swizzled 16B chunk
  const u16* kptr = Qbase + (size_t)(s * KPS + w * 16 + kk) * CC + sw * 8;
  const u16* vptr = Vbase + ((size_t)(s * KPS >> 6) * 64 + (w * 16 + kk)) * 64 + sw * 8;

#define STAGE(p, kp, vp)                                                      \
  {                                                                           \
    _Pragma("unroll")                                                         \
    for (int g = 0; g < 2; ++g) {                                             \
      __builtin_amdgcn_global_load_lds(                                       \
          (const __attribute__((address_space(1))) unsigned*)((kp) + g * 512),\
          (__attribute__((address_space(3))) unsigned*)&KT[p][(w * 16 + g * 8) * 64], \
          16, 0, 0);                                                          \
      __builtin_amdgcn_global_load_lds(                                       \
          (const __attribute__((address_space(1))) unsigned*)((vp) + g * 512),\
          (__attribute__((address_space(3))) unsigned*)&VT[p][(w * 16 + g * 8) * 64], \
          16, 0, 0);                                                          \
    }                                                                         \
  }

  STAGE(0, kptr, vptr)
  const int cs = col & 7;
  u16* PBw = &PB[w][0];
#pragma unroll 2
  for (int i = 0; i < ITERS; ++i) {
    __syncthreads();  // own vmcnt drained pre-barrier -> tile i ready
    const int p = i & 1;
    if (i + 1 < ITERS) STAGE(p ^ 1, kptr + 4096, vptr + 4096)
    kptr += 4096; vptr += 4096;

    // --- QK^T (S^T form: A=K, B=Q) + exp2 + swizzled packed P-write ---
    f32x4 sx[4];
#pragma unroll
    for (int t = 0; t < 4; ++t) {
      bf16x8 ka = *(const bf16x8*)&KT[p][(t * 16 + col) * 64 + (quad ^ cs) * 8];
      bf16x8 kb = *(const bf16x8*)&KT[p][(t * 16 + col) * 64 + ((quad + 4) ^ cs) * 8];
      sx[t] = __builtin_amdgcn_mfma_f32_16x16x32_bf16(ka, qs0, zero, 0, 0, 0);
      sx[t] = __builtin_amdgcn_mfma_f32_16x16x32_bf16(kb, qs1, sx[t], 0, 0, 0);
    }
#pragma unroll
    for (int t = 0; t < 4; ++t) {
      f32x4 pv;
#pragma unroll
      for (int r = 0; r < 4; ++r) pv[r] = exp2f(sx[t][r] - m_sc);
      l_loc += pv[0] + pv[1] + pv[2] + pv[3];
      u32x2 d;
      d[0] = __builtin_amdgcn_perm(fbits(pv[1]), fbits(pv[0]), 0x07060302u);
      d[1] = __builtin_amdgcn_perm(fbits(pv[3]), fbits(pv[2]), 0x07060302u);
      // keys t*16+quad*4..+3 = chunk (t*2 + (quad>>1)), half (quad&1)
      *(u32x2*)&PBw[col * 64 + ((t * 2 + (quad >> 1)) ^ cs) * 8 + (quad & 1) * 4] = d;
    }
    // --- P A-frags (per-wave DS in-order; swizzled chunk addressing) ---
    bf16x8 pf0 = *(const bf16x8*)&PBw[col * 64 + (quad ^ cs) * 8];
    bf16x8 pf1 = *(const bf16x8*)&PBw[col * 64 + ((quad + 4) ^ cs) * 8];
    // --- PV: O[16][64] += P[16][64] * V[64][64] ---
#pragma unroll
    for (int cg = 0; cg < 4; ++cg) {
      bf16x8 va = *(const bf16x8*)&VT[p][(cg * 16 + col) * 64 + (quad ^ cs) * 8];
      bf16x8 vb = *(const bf16x8*)&VT[p][(cg * 16 + col) * 64 + ((quad + 4) ^ cs) * 8];
      acc[cg] = __builtin_amdgcn_mfma_f32_16x16x32_bf16(pf0, va, acc[cg], 0, 0, 0);
      acc[cg] = __builtin_amdgcn_mfma_f32_16x16x32_bf16(pf1, vb, acc[cg], 0, 0, 0);
    }
  }
#undef STAGE

  // --- finalize l (2 shuffles) and write partials ---
  size_t pbase = (((size_t)(b * 64 + rg)) * S + s) * (64 * 64);
  size_t lbase = (((size_t)(b * 64 + rg)) * S + s) * 64;
  {
    float l = l_loc;
    l += __shfl_xor(l, 16);
    l += __shfl_xor(l, 32);
    if (quad == 0) lpart[lbase + w * 16 + col] = l;
  }
#pragma unroll
  for (int r = 0; r < 4; ++r) {
    int lr = w * 16 + quad * 4 + r;
    size_t o = pbase + (size_t)lr * 64;
    Opart[o + col]      = f2bf(acc[0][r]);
    Opart[o + col + 16] = f2bf(acc[1][r]);
    Opart[o + col + 32] = f2bf(acc[2][r]);
    Opart[o + col + 48] = f2bf(acc[3][r]);
  }
}

// ---------------------------------------------------------------------------
// Epilogue: out = gamma * (sum_s O)/(sum_s l) + x. 512 blocks x 256 threads.
// ---------------------------------------------------------------------------
template <int S>
__global__ __launch_bounds__(256) void epi_kernel(
    const float* __restrict__ x, const float* __restrict__ gamma,
    const u16* __restrict__ Opart, const float* __restrict__ lpart,
    float* __restrict__ out) {
  int t = blockIdx.x * 256 + threadIdx.x;  // [0, B*NN*16)
  int cg = t & 15;
  int n = (t >> 4) & (NN - 1);
  int b = t >> 16;
  int rb = n >> 6, lr = n & 63;
  size_t obase = ((size_t)(b * 64 + rb) * S) * 4096 + (size_t)lr * 64 + cg * 4;
  size_t lbase = ((size_t)(b * 64 + rb) * S) * 64 + lr;
  f32x4 sO = {0.f, 0.f, 0.f, 0.f};
  float sL = 0.f;
#pragma unroll
  for (int s = 0; s < S; ++s) {
    u16x4 o4 = *(const u16x4*)(Opart + obase + (size_t)s * 4096);
    sL += lpart[lbase + s * 64];
    sO[0] += bf2f((short)o4[0]); sO[1] += bf2f((short)o4[1]);
    sO[2] += bf2f((short)o4[2]); sO[3] += bf2f((short)o4[3]);
  }
  size_t xi = (((size_t)b * NN + n) * CC + cg * 4);
  f32x4 xv = *(const f32x4*)(x + xi);
  float g = gamma[0], inv = 1.f / sL;
  f32x4 ov;
#pragma unroll
  for (int j = 0; j < 4; ++j) ov[j] = g * (sO[j] * inv) + xv[j];
  *(f32x4*)(((float*)out) + xi) = ov;
}

// ---------------------------------------------------------------------------
// Tier B (2MB <= ws): single-kernel path. Tier C: workspace-free.
// ---------------------------------------------------------------------------
template <int WPB>
__global__ __launch_bounds__(WPB * 64, 4) void attn_fast(
    const float* __restrict__ x, const float* __restrict__ gamma,
    const u16* __restrict__ Qb, const u16* __restrict__ Vt,
    float* __restrict__ out) {
  const int w = threadIdx.x >> 6;
  const int lane = threadIdx.x & 63;
  const int quad = lane >> 4, col = lane & 15;
  const int b = blockIdx.x >> 8;
  const int tile = (blockIdx.x & 255) << 4;

  extern __shared__ char smem[];
  float* Osh = (float*)smem;
  float* lsh = Osh + WPB * 1024;
  u16* pl = (u16*)(lsh + WPB * 16) + w * 2176;

  const size_t xoff = (size_t)b * NN * CC;
  const u16* Qbase = Qb + xoff;
  const u16* Vbase = Vt + xoff;

  bf16x8 qf0 = *(const bf16x8*)(Qbase + (size_t)(tile + col) * CC + quad * 8);
  bf16x8 qf1 = *(const bf16x8*)(Qbase + (size_t)(tile + col) * CC + 32 + quad * 8);

  float msum = 0.f;
#pragma unroll
  for (int j = 0; j < 8; ++j) {
    float a = bf2f(qf0[j]), c = bf2f(qf1[j]);
    msum += a * a + c * c;
  }
  msum += __shfl_xor(msum, 16);
  msum += __shfl_xor(msum, 32);
  float m_i[4];
#pragma unroll
  for (int r = 0; r < 4; ++r) m_i[r] = __shfl(msum, quad * 4 + r);

  f32x4 zero = {0.f, 0.f, 0.f, 0.f};
  f32x4 acc[4] = {zero, zero, zero, zero};
  float l_i[4] = {0.f, 0.f, 0.f, 0.f};

  const int k0 = w * (NN / WPB);
#pragma unroll 2
  for (int kt = k0; kt < k0 + NN / WPB; kt += 64) {
    u16* plc = pl + ((kt >> 6) & 1) * 1088;
    f32x4 sx[4];
#pragma unroll
    for (int t = 0; t < 4; ++t) {
      const u16* kp = Qbase + (size_t)(kt + t * 16 + col) * CC + quad * 8;
      bf16x8 ka = *(const bf16x8*)kp;
      bf16x8 kb = *(const bf16x8*)(kp + 32);
      sx[t] = __builtin_amdgcn_mfma_f32_16x16x32_bf16(qf0, ka, zero, 0, 0, 0);
      sx[t] = __builtin_amdgcn_mfma_f32_16x16x32_bf16(qf1, kb, sx[t], 0, 0, 0);
    }
#pragma unroll
    for (int t = 0; t < 4; ++t) {
#pragma unroll
      for (int r = 0; r < 4; ++r) {
        float p = __expf(sx[t][r] - m_i[r]);
        l_i[r] += p;
        plc[(quad * 4 + r) * 68 + t * 16 + col] = f2bf(p);
      }
    }
    bf16x8 pf0 = *(const bf16x8*)(plc + col * 68 + quad * 8);
    bf16x8 pf1 = *(const bf16x8*)(plc + col * 68 + 32 + quad * 8);
#pragma unroll
    for (int cg = 0; cg < 4; ++cg) {
      const u16* vp = Vbase + (((size_t)(kt >> 6)) * 64 + cg * 16 + col) * 64 + quad * 8;
      bf16x8 v0 = *(const bf16x8*)vp;
      bf16x8 v1 = *(const bf16x8*)(vp + 32);
      acc[cg] = __builtin_amdgcn_mfma_f32_16x16x32_bf16(pf0, v0, acc[cg], 0, 0, 0);
      acc[cg] = __builtin_amdgcn_mfma_f32_16x16x32_bf16(pf1, v1, acc[cg], 0, 0, 0);
    }
  }

#pragma unroll
  for (int r = 0; r < 4; ++r)
#pragma unroll
    for (int off = 1; off < 16; off <<= 1) l_i[r] += __shfl_xor(l_i[r], off, 16);
#pragma unroll
  for (int r = 0; r < 4; ++r) {
    int row = quad * 4 + r;
    Osh[(w * 16 + row) * 64 + col]      = acc[0][r];
    Osh[(w * 16 + row) * 64 + col + 16] = acc[1][r];
    Osh[(w * 16 + row) * 64 + col + 32] = acc[2][r];
    Osh[(w * 16 + row) * 64 + col + 48] = acc[3][r];
    if (col == 0) lsh[w * 16 + row] = l_i[r];
  }
  __syncthreads();

  float g = gamma[0];
  for (int row = w; row < 16; row += WPB) {
    float L = 0.f, val = 0.f;
#pragma unroll
    for (int w2 = 0; w2 < WPB; ++w2) {
      L += lsh[w2 * 16 + row];
      val += Osh[(w2 * 16 + row) * 64 + lane];
    }
    size_t o = xoff + (size_t)(tile + row) * CC + lane;
    out[o] = g * (val / L) + x[o];
  }
}

template <int WPB>
__global__ __launch_bounds__(512) void attn_fb(const float* __restrict__ x,
                                               const float* __restrict__ gamma,
                                               float* __restrict__ out) {
  const int w = threadIdx.x >> 6;
  const int lane = threadIdx.x & 63;
  const int quad = lane >> 4, col = lane & 15;
  const int b = blockIdx.x >> 8;
  const int tile = (blockIdx.x & 255) << 4;

  extern __shared__ char smem[];
  float* Osh = (float*)smem;
  float* msh = Osh + WPB * 1024;
  float* lsh = msh + WPB * 16;
  u16* pl = (u16*)(lsh + WPB * 16) + w * 768;
  u16* vt = (u16*)(lsh + WPB * 16) + WPB * 768 + w * 2176;

  const size_t xoff = (size_t)b * NN * CC;
  const f32x4* x4 = (const f32x4*)(x + xoff);

  bf16x8 qf0, qf1;
  {
    int ri = (tile + col) * 16 + quad * 2;
    qf0 = cvt8(x4[ri], x4[ri + 1]);
    qf1 = cvt8(x4[ri + 8], x4[ri + 9]);
  }
  f32x4 zero = {0.f, 0.f, 0.f, 0.f};
  f32x4 acc0 = zero, acc1 = zero, acc2 = zero, acc3 = zero;
  float m_i[4], l_i[4];
#pragma unroll
  for (int r = 0; r < 4; ++r) { m_i[r] = -1e30f; l_i[r] = 0.f; }

  const int k0 = w * (NN / WPB);
  for (int kt = k0; kt < k0 + NN / WPB; kt += 32) {
    bf16x8 k00, k01, k10, k11;
    {
      int kb = (kt + col) * 16 + quad * 2;
      k00 = cvt8(x4[kb], x4[kb + 1]);
      k01 = cvt8(x4[kb + 8], x4[kb + 9]);
      k10 = cvt8(x4[kb + 256], x4[kb + 257]);
      k11 = cvt8(x4[kb + 264], x4[kb + 265]);
#pragma unroll
      for (int h = 0; h < 2; ++h) {
        bf16x8 va = h ? k10 : k00, vb = h ? k11 : k01;
        int base = (h * 16 + col) * 68 + quad * 8;
        *(bf16x4*)(vt + base) = __builtin_shufflevector(va, va, 0, 1, 2, 3);
        *(bf16x4*)(vt + base + 4) = __builtin_shufflevector(va, va, 4, 5, 6, 7);
        *(bf16x4*)(vt + base + 32) = __builtin_shufflevector(vb, vb, 0, 1, 2, 3);
        *(bf16x4*)(vt + base + 36) = __builtin_shufflevector(vb, vb, 4, 5, 6, 7);
      }
    }
    f32x4 s0 = zero, s1 = zero;
    s0 = __builtin_amdgcn_mfma_f32_16x16x32_bf16(qf0, k00, s0, 0, 0, 0);
    s0 = __builtin_amdgcn_mfma_f32_16x16x32_bf16(qf1, k01, s0, 0, 0, 0);
    s1 = __builtin_amdgcn_mfma_f32_16x16x32_bf16(qf0, k10, s1, 0, 0, 0);
    s1 = __builtin_amdgcn_mfma_f32_16x16x32_bf16(qf1, k11, s1, 0, 0, 0);

    float p0[4], p1[4], alpha[4];
#pragma unroll
    for (int r = 0; r < 4; ++r) {
      float mx = fmaxf(s0[r], s1[r]);
#pragma unroll
      for (int off = 1; off < 16; off <<= 1) mx = fmaxf(mx, __shfl_xor(mx, off, 16));
      float mn = fmaxf(m_i[r], mx);
      alpha[r] = __expf(m_i[r] - mn);
      p0[r] = __expf(s0[r] - mn);
      p1[r] = __expf(s1[r] - mn);
      float rs = p0[r] + p1[r];
#pragma unroll
      for (int off = 1; off < 16; off <<= 1) rs += __shfl_xor(rs, off, 16);
      l_i[r] = l_i[r] * alpha[r] + rs;
      m_i[r] = mn;
    }
#pragma unroll
    for (int r = 0; r < 4; ++r) {
      acc0[r] *= alpha[r]; acc1[r] *= alpha[r];
      acc2[r] *= alpha[r]; acc3[r] *= alpha[r];
    }
#pragma unroll
    for (int r = 0; r < 4; ++r) {
      pl[(quad * 4 + r) * 24 + col] = f2bf(p0[r]);
      pl[384 + (quad * 4 + r) * 24 + col] = f2bf(p1[r]);
    }
    bf16x8 pf = *(const bf16x8*)(pl + (quad >> 1) * 384 + col * 24 + (quad & 1) * 8);

    bf16x8 v0, v1, v2, v3;
#pragma unroll
    for (int j = 0; j < 8; ++j) {
      int rb = (quad * 8 + j) * 68 + col;
      v0[j] = (short)vt[rb];
      v1[j] = (short)vt[rb + 16];
      v2[j] = (short)vt[rb + 32];
      v3[j] = (short)vt[rb + 48];
    }
    acc0 = __builtin_amdgcn_mfma_f32_16x16x32_bf16(pf, v0, acc0, 0, 0, 0);
    acc1 = __builtin_amdgcn_mfma_f32_16x16x32_bf16(pf, v1, acc1, 0, 0, 0);
    acc2 = __builtin_amdgcn_mfma_f32_16x16x32_bf16(pf, v2, acc2, 0, 0, 0);
    acc3 = __builtin_amdgcn_mfma_f32_16x16x32_bf16(pf, v3, acc3, 0, 0, 0);
  }

#pragma unroll
  for (int r = 0; r < 4; ++r) {
    int row = quad * 4 + r;
    Osh[(w * 16 + row) * 64 + col] = acc0[r];
    Osh[(w * 16 + row) * 64 + col + 16] = acc1[r];
    Osh[(w * 16 + row) * 64 + col + 32] = acc2[r];
    Osh[(w * 16 + row) * 64 + col + 48] = acc3[r];
    if (col == 0) { msh[w * 16 + row] = m_i[r]; lsh[w * 16 + row] = l_i[r]; }
  }
  __syncthreads();

  float g = gamma[0];
  for (int row = w; row < 16; row += WPB) {
    float M = -1e30f;
#pragma unroll
    for (int w2 = 0; w2 < WPB; ++w2) M = fmaxf(M, msh[w2 * 16 + row]);
    float L = 0.f, val = 0.f;
#pragma unroll
    for (int w2 = 0; w2 < WPB; ++w2) {
      float e = __expf(msh[w2 * 16 + row] - M);
      L += lsh[w2 * 16 + row] * e;
      val += Osh[(w2 * 16 + row) * 64 + lane] * e;
    }
    size_t o = xoff + (size_t)(tile + row) * CC + lane;
    out[o] = g * (val / L) + x[o];
  }
}

extern "C" void kernel_launch(void* const* d_in, const int* in_sizes, int n_in,
                              void* d_out, int out_size, void* d_ws, size_t ws_size,
                              hipStream_t stream) {
  const float* x = (const float*)d_in[0];
  const float* gamma = (const float*)d_in[1];
  float* out = (float*)d_out;

  constexpr int S = 8;
  constexpr size_t kQV = (size_t)2 * 2 * NN * CC * sizeof(u16);         // 2 MB
  constexpr size_t kOp = (size_t)2 * 64 * S * 64 * 64 * sizeof(u16);    // 8 MB
  constexpr size_t kLp = (size_t)2 * 64 * S * 64 * sizeof(float);       // 256 KB
  if (ws_size >= kQV + kOp + kLp) {
    u16* Qb = (u16*)d_ws;
    u16* Vt = Qb + (size_t)2 * NN * CC;
    u16* Opart = (u16*)((char*)d_ws + kQV);
    float* lpart = (float*)((char*)d_ws + kQV + kOp);
    prep_kernel<<<512, 256, 0, stream>>>(x, Qb, Vt);
    attn_split<S><<<2 * 64 * S, 256, 0, stream>>>(Qb, Vt, Opart, lpart);
    epi_kernel<S><<<(2 * NN * 16) / 256, 256, 0, stream>>>(x, gamma, Opart, lpart, out);
  } else if (ws_size >= kQV) {
    u16* Qb = (u16*)d_ws;
    u16* Vt = Qb + (size_t)2 * NN * CC;
    prep_kernel<<<512, 256, 0, stream>>>(x, Qb, Vt);
    constexpr int SM = 8 * 1024 * 4 + 8 * 16 * 4 + 8 * 2176 * 2;  // 68096 B
    attn_fast<8><<<512, 512, SM, stream>>>(x, gamma, Qb, Vt, out);
  } else {
    constexpr int SM4 = 4 * (1024 + 32) * 4 + 4 * 768 * 2 + 4 * 2176 * 2;
    attn_fb<4><<<512, 256, SM4, stream>>>(x, gamma, out);
  }
}